// Round 1
// baseline (2163.614 us; speedup 1.0000x reference)
//
#include <hip/hip_runtime.h>
#include <hip/hip_bf16.h>
#include <math.h>

#define Tn 1024
#define Hn 2048
#define En 64
#define Kn 6
#define In 1024
#define Gn 8
#define TGn 3
#define Cn 256
#define Sn 2048
#define RSF 2.5

typedef __bf16 bf16x8 __attribute__((ext_vector_type(8)));
typedef short s16x8 __attribute__((ext_vector_type(8)));
typedef float f32x4 __attribute__((ext_vector_type(4)));

__device__ __forceinline__ unsigned short f2bf(float f) {
  unsigned int u = __float_as_uint(f);
  u += 0x7fffu + ((u >> 16) & 1u);
  return (unsigned short)(u >> 16);
}

// swizzled byte offset within a [rows][64 bf16] (128B-row) LDS tile
__device__ __forceinline__ int swz(int row, int kbyte) {
  return row * 128 + (kbyte ^ ((row & 7) << 4));
}

// ---------------- router: scores = sigmoid(x @ gate_w^T), fp64 accumulate ----------------
__global__ void scores_kernel(const float* __restrict__ x, const float* __restrict__ gw,
                              double* __restrict__ sc) {
  __shared__ float xs[Hn];
  int t = blockIdx.x;
  for (int i = threadIdx.x * 4; i < Hn; i += 64 * 4)
    *(float4*)(xs + i) = *(const float4*)(x + (size_t)t * Hn + i);
  __syncthreads();
  int e = threadIdx.x;
  const float* w = gw + (size_t)e * Hn;
  double acc = 0.0;
  for (int i = 0; i < Hn; i += 4) {
    float4 b = *(const float4*)(w + i);
    acc += (double)xs[i] * b.x + (double)xs[i + 1] * b.y +
           (double)xs[i + 2] * b.z + (double)xs[i + 3] * b.w;
  }
  sc[t * En + e] = 1.0 / (1.0 + exp(-acc));
}

// ---------------- grouped top-k (noaux_tc) ----------------
__global__ void topk_kernel(const double* __restrict__ sc_all, const float* __restrict__ bias,
                            int* __restrict__ ids, float* __restrict__ tw) {
  int t = blockIdx.x * blockDim.x + threadIdx.x;
  if (t >= Tn) return;
  const double* srow = sc_all + (size_t)t * En;
  double sc[En];
  for (int e = 0; e < En; ++e) sc[e] = srow[e] + (double)bias[e];
  double gsum[Gn];
  for (int g = 0; g < Gn; ++g) {
    double m1 = -1e300, m2 = -1e300;
    for (int j = 0; j < 8; ++j) {
      double v = sc[g * 8 + j];
      if (v > m1) { m2 = m1; m1 = v; } else if (v > m2) m2 = v;
    }
    gsum[g] = m1 + m2;
  }
  unsigned gsel = 0;
  for (int it = 0; it < TGn; ++it) {
    double best = -1e300; int bi = 0;
    for (int g = 0; g < Gn; ++g)
      if (!((gsel >> g) & 1) && gsum[g] > best) { best = gsum[g]; bi = g; }
    gsel |= 1u << bi;
  }
  unsigned long long taken = 0ull;
  int sel[Kn]; double w[Kn]; double wsum = 0.0;
  for (int k = 0; k < Kn; ++k) {
    double best = -1e300; int bi = 0;
    for (int e = 0; e < En; ++e) {
      if (!((gsel >> (e >> 3)) & 1)) continue;
      if ((taken >> e) & 1) continue;
      if (sc[e] > best) { best = sc[e]; bi = e; }
    }
    taken |= 1ull << bi;
    sel[k] = bi;
    w[k] = srow[bi];
    wsum += w[k];
  }
  double inv = RSF / (wsum + 1e-20);
  for (int k = 0; k < Kn; ++k) {
    ids[t * Kn + k] = sel[k];
    tw[t * Kn + k] = (float)(w[k] * inv);
  }
}

// ---------------- dispatch: capacity buffers, cumsum position semantics ----------------
__global__ void dispatch_kernel(const int* __restrict__ ids, const float* __restrict__ tw,
                                int* __restrict__ etok, float* __restrict__ ewt,
                                int* __restrict__ ecnt) {
  int e = threadIdx.x;  // 64 threads, 1 block
  int cnt = 0;
  for (int f = 0; f < Tn * Kn; ++f) {
    if (ids[f] == e) {
      if (cnt < Cn) { etok[e * Cn + cnt] = f / Kn; ewt[e * Cn + cnt] = tw[f]; }
      ++cnt;
    }
  }
  int cc = cnt < Cn ? cnt : Cn;
  for (int c = cc; c < Cn; ++c) { etok[e * Cn + c] = -1; ewt[e * Cn + c] = 0.f; }
  ecnt[e] = cc;
}

// ---------------- GEMM1: (gathered) x @ W13, fused SiLU*mul, bf16 out ----------------
__global__ __launch_bounds__(256, 2)
void gemm1_silu(const float* __restrict__ A, const int* __restrict__ rows,
                const int* __restrict__ ecnt, const float* __restrict__ B,
                unsigned short* __restrict__ O, int Kd, int Nhalf,
                long long Bstride, long long Ostride) {
  int e = blockIdx.z;
  int m0 = blockIdx.y * 128, n0 = blockIdx.x * 128;
  if (ecnt && ecnt[e] <= m0) return;
  const float* Bp = B + (long long)e * Bstride;
  unsigned short* Op = O + (long long)e * Ostride;

  __shared__ char AsB[128 * 128];
  __shared__ char BgB[128 * 128];
  __shared__ char BuB[128 * 128];
  __shared__ int rowix[128];

  int tid = threadIdx.x;
  if (tid < 128) {
    int r;
    if (rows) { int v = rows[e * Cn + m0 + tid]; r = v < 0 ? 0 : v; }
    else r = m0 + tid;
    rowix[tid] = r;
  }

  int lane = tid & 63, wv = tid >> 6;
  int wr = wv >> 1, wc = wv & 1;
  int l15 = lane & 15, lhi = lane >> 4;
  int hi = (lane >> 5) & 1, cc4 = (lane & 31) * 4;
  int ldb = 2 * Nhalf;

  f32x4 zero = {0.f, 0.f, 0.f, 0.f};
  f32x4 accg[4][4], accu[4][4];
#pragma unroll
  for (int i = 0; i < 4; ++i)
#pragma unroll
    for (int j = 0; j < 4; ++j) { accg[i][j] = zero; accu[i][j] = zero; }

  __syncthreads();

  for (int k0 = 0; k0 < Kd; k0 += 64) {
    // stage A (128 x 64 fp32 -> bf16), coalesced 8 threads/row
#pragma unroll
    for (int it = 0; it < 4; ++it) {
      int chunk = it * 256 + tid;
      int row = chunk >> 3;
      int kc = (chunk & 7) * 8;
      const float* src = A + (size_t)rowix[row] * Hn + k0 + kc;
      float4 v0 = *(const float4*)src;
      float4 v1 = *(const float4*)(src + 4);
      s16x8 h;
      h[0] = f2bf(v0.x); h[1] = f2bf(v0.y); h[2] = f2bf(v0.z); h[3] = f2bf(v0.w);
      h[4] = f2bf(v1.x); h[5] = f2bf(v1.y); h[6] = f2bf(v1.z); h[7] = f2bf(v1.w);
      *(s16x8*)(AsB + swz(row, kc * 2)) = h;
    }
    // stage Bg / Bu with register transpose -> [n][k] layout
    int kb = 16 * wv + 8 * hi;  // 0..56
    {
      float4 q[8];
#pragma unroll
      for (int r = 0; r < 8; ++r)
        q[r] = *(const float4*)(Bp + (size_t)(k0 + kb + r) * ldb + n0 + cc4);
#pragma unroll
      for (int j = 0; j < 4; ++j) {
        s16x8 col;
#pragma unroll
        for (int r = 0; r < 8; ++r) col[r] = f2bf(((const float*)&q[r])[j]);
        *(s16x8*)(BgB + swz(cc4 + j, kb * 2)) = col;
      }
#pragma unroll
      for (int r = 0; r < 8; ++r)
        q[r] = *(const float4*)(Bp + (size_t)(k0 + kb + r) * ldb + Nhalf + n0 + cc4);
#pragma unroll
      for (int j = 0; j < 4; ++j) {
        s16x8 col;
#pragma unroll
        for (int r = 0; r < 8; ++r) col[r] = f2bf(((const float*)&q[r])[j]);
        *(s16x8*)(BuB + swz(cc4 + j, kb * 2)) = col;
      }
    }
    __syncthreads();
#pragma unroll
    for (int kk = 0; kk < 64; kk += 32) {
      int kbyte = kk * 2 + 16 * lhi;
      bf16x8 af[4], bg[4], bu[4];
#pragma unroll
      for (int m = 0; m < 4; ++m)
        af[m] = *(const bf16x8*)(AsB + swz(wr * 64 + m * 16 + l15, kbyte));
#pragma unroll
      for (int n = 0; n < 4; ++n) {
        bg[n] = *(const bf16x8*)(BgB + swz(wc * 64 + n * 16 + l15, kbyte));
        bu[n] = *(const bf16x8*)(BuB + swz(wc * 64 + n * 16 + l15, kbyte));
      }
#pragma unroll
      for (int m = 0; m < 4; ++m)
#pragma unroll
        for (int n = 0; n < 4; ++n) {
          accg[m][n] = __builtin_amdgcn_mfma_f32_16x16x32_bf16(af[m], bg[n], accg[m][n], 0, 0, 0);
          accu[m][n] = __builtin_amdgcn_mfma_f32_16x16x32_bf16(af[m], bu[n], accu[m][n], 0, 0, 0);
        }
    }
    __syncthreads();
  }
#pragma unroll
  for (int m = 0; m < 4; ++m)
#pragma unroll
    for (int n = 0; n < 4; ++n)
#pragma unroll
      for (int r = 0; r < 4; ++r) {
        int row = m0 + wr * 64 + m * 16 + lhi * 4 + r;
        int col = n0 + wc * 64 + n * 16 + l15;
        float g = accg[m][n][r], u = accu[m][n][r];
        float v = g / (1.f + __expf(-g)) * u;
        Op[(size_t)row * Nhalf + col] = f2bf(v);
      }
}

// ---------------- GEMM2: h_mid @ W2 (scatter-atomic) or smid @ shared_down (store) ----------------
__global__ __launch_bounds__(256, 2)
void gemm2_kernel(const unsigned short* __restrict__ A, const float* __restrict__ B,
                  const int* __restrict__ etok, const float* __restrict__ ewt,
                  const int* __restrict__ ecnt, float* __restrict__ out, int Kd,
                  long long Astride, long long Bstride) {
  int e = blockIdx.z;
  int m0 = blockIdx.y * 128, n0 = blockIdx.x * 128;
  if (ecnt && ecnt[e] <= m0) return;
  const unsigned short* Ap = A + (long long)e * Astride;
  const float* Bp = B + (long long)e * Bstride;

  __shared__ char AsB[128 * 128];
  __shared__ char BsB[128 * 128];
  __shared__ int s_tok[128];
  __shared__ float s_wt[128];

  int tid = threadIdx.x;
  if (tid < 128) {
    if (etok) { s_tok[tid] = etok[e * Cn + m0 + tid]; s_wt[tid] = ewt[e * Cn + m0 + tid]; }
    else { s_tok[tid] = m0 + tid; s_wt[tid] = 1.f; }
  }

  int lane = tid & 63, wv = tid >> 6;
  int wr = wv >> 1, wc = wv & 1;
  int l15 = lane & 15, lhi = lane >> 4;
  int hi = (lane >> 5) & 1, cc4 = (lane & 31) * 4;

  f32x4 zero = {0.f, 0.f, 0.f, 0.f};
  f32x4 acc[4][4];
#pragma unroll
  for (int i = 0; i < 4; ++i)
#pragma unroll
    for (int j = 0; j < 4; ++j) acc[i][j] = zero;

  __syncthreads();

  for (int k0 = 0; k0 < Kd; k0 += 64) {
#pragma unroll
    for (int it = 0; it < 4; ++it) {
      int chunk = it * 256 + tid;
      int row = chunk >> 3;
      int kc = (chunk & 7) * 8;
      *(s16x8*)(AsB + swz(row, kc * 2)) =
          *(const s16x8*)(Ap + (size_t)(m0 + row) * Kd + k0 + kc);
    }
    int kb = 16 * wv + 8 * hi;
    {
      float4 q[8];
#pragma unroll
      for (int r = 0; r < 8; ++r)
        q[r] = *(const float4*)(Bp + (size_t)(k0 + kb + r) * Hn + n0 + cc4);
#pragma unroll
      for (int j = 0; j < 4; ++j) {
        s16x8 col;
#pragma unroll
        for (int r = 0; r < 8; ++r) col[r] = f2bf(((const float*)&q[r])[j]);
        *(s16x8*)(BsB + swz(cc4 + j, kb * 2)) = col;
      }
    }
    __syncthreads();
#pragma unroll
    for (int kk = 0; kk < 64; kk += 32) {
      int kbyte = kk * 2 + 16 * lhi;
      bf16x8 af[4], bf[4];
#pragma unroll
      for (int m = 0; m < 4; ++m)
        af[m] = *(const bf16x8*)(AsB + swz(wr * 64 + m * 16 + l15, kbyte));
#pragma unroll
      for (int n = 0; n < 4; ++n)
        bf[n] = *(const bf16x8*)(BsB + swz(wc * 64 + n * 16 + l15, kbyte));
#pragma unroll
      for (int m = 0; m < 4; ++m)
#pragma unroll
        for (int n = 0; n < 4; ++n)
          acc[m][n] = __builtin_amdgcn_mfma_f32_16x16x32_bf16(af[m], bf[n], acc[m][n], 0, 0, 0);
    }
    __syncthreads();
  }
#pragma unroll
  for (int m = 0; m < 4; ++m)
#pragma unroll
    for (int n = 0; n < 4; ++n)
#pragma unroll
      for (int r = 0; r < 4; ++r) {
        int lrow = wr * 64 + m * 16 + lhi * 4 + r;
        int col = n0 + wc * 64 + n * 16 + l15;
        float v = acc[m][n][r];
        if (etok) {
          int tok = s_tok[lrow];
          if (tok >= 0) atomicAdd(out + (size_t)tok * Hn + col, s_wt[lrow] * v);
        } else {
          out[(size_t)(m0 + lrow) * Hn + col] = v;
        }
      }
}

extern "C" void kernel_launch(void* const* d_in, const int* in_sizes, int n_in,
                              void* d_out, int out_size, void* d_ws, size_t ws_size,
                              hipStream_t stream) {
  (void)in_sizes; (void)n_in; (void)out_size; (void)ws_size;
  const float* x   = (const float*)d_in[0];
  const float* gw  = (const float*)d_in[1];
  const float* gb  = (const float*)d_in[2];
  const float* w13 = (const float*)d_in[3];
  const float* w2  = (const float*)d_in[4];
  const float* sgu = (const float*)d_in[5];
  const float* sdn = (const float*)d_in[6];
  float* out = (float*)d_out;

  char* ws = (char*)d_ws;
  size_t off = 0;
  double* scores = (double*)(ws + off); off += (size_t)Tn * En * 8;
  int* ids   = (int*)(ws + off);   off += (size_t)Tn * Kn * 4;
  float* tw  = (float*)(ws + off); off += (size_t)Tn * Kn * 4;
  int* etok  = (int*)(ws + off);   off += (size_t)En * Cn * 4;
  float* ewt = (float*)(ws + off); off += (size_t)En * Cn * 4;
  int* ecnt  = (int*)(ws + off);   off += 256;
  unsigned short* hmid = (unsigned short*)(ws + off); off += (size_t)En * Cn * In * 2;
  unsigned short* smid = (unsigned short*)(ws + off); off += (size_t)Tn * Sn * 2;

  scores_kernel<<<Tn, 64, 0, stream>>>(x, gw, scores);
  topk_kernel<<<Tn / 256, 256, 0, stream>>>(scores, gb, ids, tw);
  dispatch_kernel<<<1, 64, 0, stream>>>(ids, tw, etok, ewt, ecnt);

  // expert gate_up + SiLU*mul -> hmid  [E,C,I] bf16
  gemm1_silu<<<dim3(In / 128, Cn / 128, En), 256, 0, stream>>>(
      x, etok, ecnt, w13, hmid, Hn, In, (long long)Hn * 2 * In, (long long)Cn * In);
  // shared gate_up + SiLU*mul -> smid  [T,S] bf16
  gemm1_silu<<<dim3(Sn / 128, Tn / 128, 1), 256, 0, stream>>>(
      x, nullptr, nullptr, sgu, smid, Hn, Sn, 0, 0);
  // shared down -> out (direct store, initializes out)
  gemm2_kernel<<<dim3(Hn / 128, Tn / 128, 1), 256, 0, stream>>>(
      smid, sdn, nullptr, nullptr, nullptr, out, Sn, 0, 0);
  // expert down -> scatter atomic add into out
  gemm2_kernel<<<dim3(Hn / 128, Cn / 128, En), 256, 0, stream>>>(
      hmid, w2, etok, ewt, ecnt, out, In, (long long)Cn * In, (long long)In * Hn);
}

// Round 2
// 668.263 us; speedup vs baseline: 3.2377x; 3.2377x over previous
//
#include <hip/hip_runtime.h>
#include <hip/hip_bf16.h>
#include <math.h>

#define Tn 1024
#define Hn 2048
#define En 64
#define Kn 6
#define In 1024
#define Gn 8
#define TGn 3
#define Cn 256
#define Sn 2048
#define RSF 2.5

typedef __bf16 bf16x8 __attribute__((ext_vector_type(8)));
typedef __bf16 bf16x4 __attribute__((ext_vector_type(4)));
typedef float f32x4 __attribute__((ext_vector_type(4)));

// swizzled byte offset within a [rows][64 bf16] (128B-row) LDS tile.
// XOR pattern ((row^(row>>2))&7) gives 8 distinct slots for BOTH
// consecutive-row reads and stride-4-row writes (2-way max, free per m136).
__device__ __forceinline__ int swz(int row, int kbyte) {
  return row * 128 + (kbyte ^ ((((row >> 2) ^ row) & 7) << 4));
}

// ---------------- router: scores = sigmoid(x @ gate_w^T), fp64 accumulate ----------------
__global__ void scores_kernel(const float* __restrict__ x, const float* __restrict__ gw,
                              double* __restrict__ sc) {
  __shared__ float xs[Hn];
  int t = blockIdx.x;
  for (int i = threadIdx.x * 4; i < Hn; i += 64 * 4)
    *(float4*)(xs + i) = *(const float4*)(x + (size_t)t * Hn + i);
  __syncthreads();
  int e = threadIdx.x;
  const float* w = gw + (size_t)e * Hn;
  double a0 = 0.0, a1 = 0.0, a2 = 0.0, a3 = 0.0;
  for (int i = 0; i < Hn; i += 4) {
    float4 b = *(const float4*)(w + i);
    a0 += (double)xs[i] * b.x;
    a1 += (double)xs[i + 1] * b.y;
    a2 += (double)xs[i + 2] * b.z;
    a3 += (double)xs[i + 3] * b.w;
  }
  double acc = (a0 + a1) + (a2 + a3);
  sc[t * En + e] = 1.0 / (1.0 + exp(-acc));
}

// ---------------- grouped top-k (noaux_tc) ----------------
__global__ void topk_kernel(const double* __restrict__ sc_all, const float* __restrict__ bias,
                            int* __restrict__ ids, float* __restrict__ tw) {
  int t = blockIdx.x * blockDim.x + threadIdx.x;
  if (t >= Tn) return;
  const double* srow = sc_all + (size_t)t * En;
  double sc[En];
  for (int e = 0; e < En; ++e) sc[e] = srow[e] + (double)bias[e];
  double gsum[Gn];
  for (int g = 0; g < Gn; ++g) {
    double m1 = -1e300, m2 = -1e300;
    for (int j = 0; j < 8; ++j) {
      double v = sc[g * 8 + j];
      if (v > m1) { m2 = m1; m1 = v; } else if (v > m2) m2 = v;
    }
    gsum[g] = m1 + m2;
  }
  unsigned gsel = 0;
  for (int it = 0; it < TGn; ++it) {
    double best = -1e300; int bi = 0;
    for (int g = 0; g < Gn; ++g)
      if (!((gsel >> g) & 1) && gsum[g] > best) { best = gsum[g]; bi = g; }
    gsel |= 1u << bi;
  }
  unsigned long long taken = 0ull;
  int sel[Kn]; double w[Kn]; double wsum = 0.0;
  for (int k = 0; k < Kn; ++k) {
    double best = -1e300; int bi = 0;
    for (int e = 0; e < En; ++e) {
      if (!((gsel >> (e >> 3)) & 1)) continue;
      if ((taken >> e) & 1) continue;
      if (sc[e] > best) { best = sc[e]; bi = e; }
    }
    taken |= 1ull << bi;
    sel[k] = bi;
    w[k] = srow[bi];
    wsum += w[k];
  }
  double inv = RSF / (wsum + 1e-20);
  for (int k = 0; k < Kn; ++k) {
    ids[t * Kn + k] = sel[k];
    tw[t * Kn + k] = (float)(w[k] * inv);
  }
}

// ---------------- dispatch: parallel ballot-rank scan, cumsum position semantics ----------------
__global__ void dispatch_kernel(const int* __restrict__ ids, const float* __restrict__ tw,
                                int* __restrict__ etok, float* __restrict__ ewt,
                                int* __restrict__ ecnt) {
  int e = blockIdx.x;           // 64 blocks, one per expert
  int tid = threadIdx.x;        // 256 threads
  int lane = tid & 63, wv = tid >> 6;
  __shared__ int wcnt[4];
  int base = 0;
  for (int c = 0; c < Tn * Kn; c += 256) {
    int f = c + tid;
    bool p = (ids[f] == e);
    unsigned long long m = __ballot(p);
    int rank = __popcll(m & ((1ull << lane) - 1ull));
    if (lane == 0) wcnt[wv] = __popcll(m);
    __syncthreads();
    int woff = 0;
    for (int w = 0; w < wv; ++w) woff += wcnt[w];
    int tot = wcnt[0] + wcnt[1] + wcnt[2] + wcnt[3];
    if (p) {
      int pos = base + woff + rank;
      if (pos < Cn) { etok[e * Cn + pos] = f / Kn; ewt[e * Cn + pos] = tw[f]; }
    }
    base += tot;
    __syncthreads();
  }
  int cc = base < Cn ? base : Cn;
  for (int cpos = cc + tid; cpos < Cn; cpos += 256) {
    etok[e * Cn + cpos] = -1; ewt[e * Cn + cpos] = 0.f;
  }
  if (tid == 0) ecnt[e] = cc;
}

// ---------------- GEMM1: (gathered) x @ W13, fused SiLU*mul, bf16 out ----------------
// BM=128, BN=64 (per gate/up buffer), BK=64, 4 waves (each 32 rows x 64 cols).
// T14 schedule: loads for tile k+1 issued before MFMA on tile k.
__global__ __launch_bounds__(256, 2)
void gemm1_silu(const float* __restrict__ A, const int* __restrict__ rows,
                const int* __restrict__ ecnt, const float* __restrict__ B,
                __bf16* __restrict__ O, int Kd, int Nhalf,
                long long Bstride, long long Ostride) {
  int e = blockIdx.z;
  int m0 = blockIdx.y * 128, n0 = blockIdx.x * 64;
  if (ecnt && ecnt[e] <= m0) return;
  const float* Bp = B + (long long)e * Bstride;
  __bf16* Op = O + (long long)e * Ostride;

  __shared__ __attribute__((aligned(16))) __bf16 As[128 * 64];
  __shared__ __attribute__((aligned(16))) __bf16 Bg[64 * 64];
  __shared__ __attribute__((aligned(16))) __bf16 Bu[64 * 64];
  __shared__ int rowix[128];

  int tid = threadIdx.x;
  if (tid < 128) {
    int r;
    if (rows) { int v = rows[e * Cn + m0 + tid]; r = v < 0 ? 0 : v; }
    else r = m0 + tid;
    rowix[tid] = r;
  }
  __syncthreads();

  int lane = tid & 63;
  int wr = tid >> 6;                    // wave id: row group
  int l15 = lane & 15, lhi = lane >> 4;

  // A-load geometry: 4 its, row = (tid>>3)+32*it, kc = (tid&7)*8
  const float* arow[4];
#pragma unroll
  for (int it = 0; it < 4; ++it)
    arow[it] = A + (size_t)rowix[(tid >> 3) + 32 * it] * Hn + (tid & 7) * 8;
  int rowA = tid >> 3, kcbyte = (tid & 7) * 16;

  // B-load geometry: kb = 4 rows per thread, cB = 4 cols
  int kb = (tid >> 4) * 4;
  int cB = (tid & 15) * 4;
  size_t ldb = (size_t)2 * Nhalf;
  const float* bgp = Bp + (size_t)kb * ldb + n0 + cB;
  const float* bup = bgp + Nhalf;

  f32x4 zero = {0.f, 0.f, 0.f, 0.f};
  f32x4 accg[2][4], accu[2][4];
#pragma unroll
  for (int i = 0; i < 2; ++i)
#pragma unroll
    for (int j = 0; j < 4; ++j) { accg[i][j] = zero; accu[i][j] = zero; }

  float4 qa[4][2], qg[4], qu[4];

#define LOADS(K0)                                                          \
  {                                                                        \
    _Pragma("unroll") for (int it = 0; it < 4; ++it) {                     \
      qa[it][0] = *(const float4*)(arow[it] + (K0));                       \
      qa[it][1] = *(const float4*)(arow[it] + (K0) + 4);                   \
    }                                                                      \
    _Pragma("unroll") for (int r = 0; r < 4; ++r) {                        \
      qg[r] = *(const float4*)(bgp + (size_t)((K0) + r) * ldb);            \
      qu[r] = *(const float4*)(bup + (size_t)((K0) + r) * ldb);            \
    }                                                                      \
  }

  LOADS(0);

  for (int k0 = 0; k0 < Kd; k0 += 64) {
    // convert + LDS write (waits on in-flight loads)
#pragma unroll
    for (int it = 0; it < 4; ++it) {
      bf16x8 h;
#pragma unroll
      for (int j = 0; j < 4; ++j) {
        h[j] = (__bf16)(((const float*)&qa[it][0])[j]);
        h[4 + j] = (__bf16)(((const float*)&qa[it][1])[j]);
      }
      *(bf16x8*)((char*)As + swz(rowA + 32 * it, kcbyte)) = h;
    }
#pragma unroll
    for (int j = 0; j < 4; ++j) {
      bf16x4 cg, cu;
#pragma unroll
      for (int r = 0; r < 4; ++r) {
        cg[r] = (__bf16)(((const float*)&qg[r])[j]);
        cu[r] = (__bf16)(((const float*)&qu[r])[j]);
      }
      *(bf16x4*)((char*)Bg + swz(cB + j, kb * 2)) = cg;
      *(bf16x4*)((char*)Bu + swz(cB + j, kb * 2)) = cu;
    }
    __syncthreads();

    if (k0 + 64 < Kd) LOADS(k0 + 64);   // prefetch next tile (in flight during MFMA)

#pragma unroll
    for (int kk = 0; kk < 2; ++kk) {
      int kbyte = kk * 64 + 16 * lhi;
      bf16x8 af[2], fg[4], fu[4];
#pragma unroll
      for (int m = 0; m < 2; ++m)
        af[m] = *(const bf16x8*)((char*)As + swz(wr * 32 + m * 16 + l15, kbyte));
#pragma unroll
      for (int n = 0; n < 4; ++n) {
        fg[n] = *(const bf16x8*)((char*)Bg + swz(n * 16 + l15, kbyte));
        fu[n] = *(const bf16x8*)((char*)Bu + swz(n * 16 + l15, kbyte));
      }
#pragma unroll
      for (int m = 0; m < 2; ++m)
#pragma unroll
        for (int n = 0; n < 4; ++n) {
          accg[m][n] = __builtin_amdgcn_mfma_f32_16x16x32_bf16(af[m], fg[n], accg[m][n], 0, 0, 0);
          accu[m][n] = __builtin_amdgcn_mfma_f32_16x16x32_bf16(af[m], fu[n], accu[m][n], 0, 0, 0);
        }
    }
    __syncthreads();
  }
#undef LOADS

#pragma unroll
  for (int m = 0; m < 2; ++m)
#pragma unroll
    for (int n = 0; n < 4; ++n)
#pragma unroll
      for (int r = 0; r < 4; ++r) {
        int row = m0 + wr * 32 + m * 16 + lhi * 4 + r;
        int col = n0 + n * 16 + l15;
        float g = accg[m][n][r], u = accu[m][n][r];
        float v = g / (1.f + __expf(-g)) * u;
        Op[(size_t)row * Nhalf + col] = (__bf16)v;
      }
}

// ---------------- GEMM2: mid(bf16) @ W2/shared_down, scatter-atomic or store ----------------
// BM=128, BN=64, BK=64, 4 waves (each 32 rows x 64 cols), same T14 schedule.
__global__ __launch_bounds__(256, 2)
void gemm2_kernel(const __bf16* __restrict__ A, const float* __restrict__ B,
                  const int* __restrict__ etok, const float* __restrict__ ewt,
                  const int* __restrict__ ecnt, float* __restrict__ out, int Kd,
                  long long Astride, long long Bstride) {
  int e = blockIdx.z;
  int m0 = blockIdx.y * 128, n0 = blockIdx.x * 64;
  if (ecnt && ecnt[e] <= m0) return;
  const __bf16* Ap = A + (long long)e * Astride;
  const float* Bp = B + (long long)e * Bstride;

  __shared__ __attribute__((aligned(16))) __bf16 As[128 * 64];
  __shared__ __attribute__((aligned(16))) __bf16 Bs[64 * 64];
  __shared__ int s_tok[128];
  __shared__ float s_wt[128];

  int tid = threadIdx.x;
  if (tid < 128) {
    if (etok) { s_tok[tid] = etok[e * Cn + m0 + tid]; s_wt[tid] = ewt[e * Cn + m0 + tid]; }
    else { s_tok[tid] = m0 + tid; s_wt[tid] = 1.f; }
  }
  __syncthreads();

  int lane = tid & 63;
  int wr = tid >> 6;
  int l15 = lane & 15, lhi = lane >> 4;

  int rowA = tid >> 3, kc8 = (tid & 7) * 8;
  const __bf16* ap0 = Ap + (size_t)(m0 + rowA) * Kd + kc8;

  int kb = (tid >> 4) * 4;
  int cB = (tid & 15) * 4;
  const float* bp0 = Bp + (size_t)kb * Hn + n0 + cB;

  f32x4 zero = {0.f, 0.f, 0.f, 0.f};
  f32x4 acc[2][4];
#pragma unroll
  for (int i = 0; i < 2; ++i)
#pragma unroll
    for (int j = 0; j < 4; ++j) acc[i][j] = zero;

  bf16x8 qa[4];
  float4 qb[4];

#define LOADS2(K0)                                                          \
  {                                                                         \
    _Pragma("unroll") for (int it = 0; it < 4; ++it)                        \
      qa[it] = *(const bf16x8*)(ap0 + (size_t)(32 * it) * Kd + (K0));       \
    _Pragma("unroll") for (int r = 0; r < 4; ++r)                           \
      qb[r] = *(const float4*)(bp0 + (size_t)((K0) + r) * Hn);              \
  }

  LOADS2(0);

  for (int k0 = 0; k0 < Kd; k0 += 64) {
#pragma unroll
    for (int it = 0; it < 4; ++it)
      *(bf16x8*)((char*)As + swz(rowA + 32 * it, kc8 * 2)) = qa[it];
#pragma unroll
    for (int j = 0; j < 4; ++j) {
      bf16x4 cv;
#pragma unroll
      for (int r = 0; r < 4; ++r) cv[r] = (__bf16)(((const float*)&qb[r])[j]);
      *(bf16x4*)((char*)Bs + swz(cB + j, kb * 2)) = cv;
    }
    __syncthreads();

    if (k0 + 64 < Kd) LOADS2(k0 + 64);

#pragma unroll
    for (int kk = 0; kk < 2; ++kk) {
      int kbyte = kk * 64 + 16 * lhi;
      bf16x8 af[2], bfr[4];
#pragma unroll
      for (int m = 0; m < 2; ++m)
        af[m] = *(const bf16x8*)((char*)As + swz(wr * 32 + m * 16 + l15, kbyte));
#pragma unroll
      for (int n = 0; n < 4; ++n)
        bfr[n] = *(const bf16x8*)((char*)Bs + swz(n * 16 + l15, kbyte));
#pragma unroll
      for (int m = 0; m < 2; ++m)
#pragma unroll
        for (int n = 0; n < 4; ++n)
          acc[m][n] = __builtin_amdgcn_mfma_f32_16x16x32_bf16(af[m], bfr[n], acc[m][n], 0, 0, 0);
    }
    __syncthreads();
  }
#undef LOADS2

#pragma unroll
  for (int m = 0; m < 2; ++m)
#pragma unroll
    for (int n = 0; n < 4; ++n)
#pragma unroll
      for (int r = 0; r < 4; ++r) {
        int lrow = wr * 32 + m * 16 + lhi * 4 + r;
        int col = n0 + n * 16 + l15;
        float v = acc[m][n][r];
        if (etok) {
          int tok = s_tok[lrow];
          if (tok >= 0) atomicAdd(out + (size_t)tok * Hn + col, s_wt[lrow] * v);
        } else {
          out[(size_t)(m0 + lrow) * Hn + col] = v;
        }
      }
}

extern "C" void kernel_launch(void* const* d_in, const int* in_sizes, int n_in,
                              void* d_out, int out_size, void* d_ws, size_t ws_size,
                              hipStream_t stream) {
  (void)in_sizes; (void)n_in; (void)out_size; (void)ws_size;
  const float* x   = (const float*)d_in[0];
  const float* gw  = (const float*)d_in[1];
  const float* gb  = (const float*)d_in[2];
  const float* w13 = (const float*)d_in[3];
  const float* w2  = (const float*)d_in[4];
  const float* sgu = (const float*)d_in[5];
  const float* sdn = (const float*)d_in[6];
  float* out = (float*)d_out;

  char* ws = (char*)d_ws;
  size_t off = 0;
  double* scores = (double*)(ws + off); off += (size_t)Tn * En * 8;
  int* ids   = (int*)(ws + off);   off += (size_t)Tn * Kn * 4;
  float* tw  = (float*)(ws + off); off += (size_t)Tn * Kn * 4;
  int* etok  = (int*)(ws + off);   off += (size_t)En * Cn * 4;
  float* ewt = (float*)(ws + off); off += (size_t)En * Cn * 4;
  int* ecnt  = (int*)(ws + off);   off += 256;
  __bf16* hmid = (__bf16*)(ws + off); off += (size_t)En * Cn * In * 2;
  __bf16* smid = (__bf16*)(ws + off); off += (size_t)Tn * Sn * 2;

  scores_kernel<<<Tn, 64, 0, stream>>>(x, gw, scores);
  topk_kernel<<<Tn / 256, 256, 0, stream>>>(scores, gb, ids, tw);
  dispatch_kernel<<<En, 256, 0, stream>>>(ids, tw, etok, ewt, ecnt);

  // expert gate_up + SiLU*mul -> hmid  [E,C,I] bf16
  gemm1_silu<<<dim3(In / 64, Cn / 128, En), 256, 0, stream>>>(
      x, etok, ecnt, w13, hmid, Hn, In, (long long)Hn * 2 * In, (long long)Cn * In);
  // shared gate_up + SiLU*mul -> smid  [T,S] bf16
  gemm1_silu<<<dim3(Sn / 64, Tn / 128, 1), 256, 0, stream>>>(
      x, nullptr, nullptr, sgu, smid, Hn, Sn, 0, 0);
  // shared down -> out (direct store, initializes out)
  gemm2_kernel<<<dim3(Hn / 64, Tn / 128, 1), 256, 0, stream>>>(
      smid, sdn, nullptr, nullptr, nullptr, out, Sn, 0, 0);
  // expert down -> scatter atomic add into out
  gemm2_kernel<<<dim3(Hn / 64, Cn / 128, 64), 256, 0, stream>>>(
      hmid, w2, etok, ewt, ecnt, out, In, (long long)Cn * In, (long long)In * Hn);
}

// Round 3
// 652.568 us; speedup vs baseline: 3.3155x; 1.0241x over previous
//
#include <hip/hip_runtime.h>
#include <hip/hip_bf16.h>
#include <math.h>

#define Tn 1024
#define Hn 2048
#define En 64
#define Kn 6
#define In 1024
#define Gn 8
#define TGn 3
#define Cn 256
#define Sn 2048
#define RSF 2.5

typedef __bf16 bf16x8 __attribute__((ext_vector_type(8)));
typedef __bf16 bf16x4 __attribute__((ext_vector_type(4)));
typedef float f32x4 __attribute__((ext_vector_type(4)));

// swizzled byte offset within a [rows][64 bf16] (128B-row) LDS tile.
// XOR sel ((row^(row>>2))&7): 2-way max for both write patterns (stride-4 rows)
// and read patterns (consecutive rows) -> free per m136.
__device__ __forceinline__ int swz(int row, int kbyte) {
  return row * 128 + (kbyte ^ ((((row >> 2) ^ row) & 7) << 4));
}

// ---------------- router: scores = sigmoid(x @ gate_w^T), fp64 accumulate ----------------
__global__ void scores_kernel(const float* __restrict__ x, const float* __restrict__ gw,
                              double* __restrict__ sc) {
  __shared__ float xs[Hn];
  int t = blockIdx.x;
  for (int i = threadIdx.x * 4; i < Hn; i += 64 * 4)
    *(float4*)(xs + i) = *(const float4*)(x + (size_t)t * Hn + i);
  __syncthreads();
  int e = threadIdx.x;
  const float* w = gw + (size_t)e * Hn;
  double a0 = 0.0, a1 = 0.0, a2 = 0.0, a3 = 0.0;
  for (int i = 0; i < Hn; i += 4) {
    float4 b = *(const float4*)(w + i);
    a0 += (double)xs[i] * b.x;
    a1 += (double)xs[i + 1] * b.y;
    a2 += (double)xs[i + 2] * b.z;
    a3 += (double)xs[i + 3] * b.w;
  }
  double acc = (a0 + a1) + (a2 + a3);
  sc[t * En + e] = 1.0 / (1.0 + exp(-acc));
}

// ---------------- grouped top-k (noaux_tc) ----------------
__global__ void topk_kernel(const double* __restrict__ sc_all, const float* __restrict__ bias,
                            int* __restrict__ ids, float* __restrict__ tw) {
  int t = blockIdx.x * blockDim.x + threadIdx.x;
  if (t >= Tn) return;
  const double* srow = sc_all + (size_t)t * En;
  double sc[En];
  for (int e = 0; e < En; ++e) sc[e] = srow[e] + (double)bias[e];
  double gsum[Gn];
  for (int g = 0; g < Gn; ++g) {
    double m1 = -1e300, m2 = -1e300;
    for (int j = 0; j < 8; ++j) {
      double v = sc[g * 8 + j];
      if (v > m1) { m2 = m1; m1 = v; } else if (v > m2) m2 = v;
    }
    gsum[g] = m1 + m2;
  }
  unsigned gsel = 0;
  for (int it = 0; it < TGn; ++it) {
    double best = -1e300; int bi = 0;
    for (int g = 0; g < Gn; ++g)
      if (!((gsel >> g) & 1) && gsum[g] > best) { best = gsum[g]; bi = g; }
    gsel |= 1u << bi;
  }
  unsigned long long taken = 0ull;
  int sel[Kn]; double w[Kn]; double wsum = 0.0;
  for (int k = 0; k < Kn; ++k) {
    double best = -1e300; int bi = 0;
    for (int e = 0; e < En; ++e) {
      if (!((gsel >> (e >> 3)) & 1)) continue;
      if ((taken >> e) & 1) continue;
      if (sc[e] > best) { best = sc[e]; bi = e; }
    }
    taken |= 1ull << bi;
    sel[k] = bi;
    w[k] = srow[bi];
    wsum += w[k];
  }
  double inv = RSF / (wsum + 1e-20);
  for (int k = 0; k < Kn; ++k) {
    ids[t * Kn + k] = sel[k];
    tw[t * Kn + k] = (float)(w[k] * inv);
  }
}

// ---------------- dispatch: parallel ballot-rank scan, cumsum position semantics ----------------
__global__ void dispatch_kernel(const int* __restrict__ ids, const float* __restrict__ tw,
                                int* __restrict__ etok, float* __restrict__ ewt,
                                int* __restrict__ ecnt) {
  int e = blockIdx.x;           // 64 blocks, one per expert
  int tid = threadIdx.x;        // 256 threads
  int lane = tid & 63, wv = tid >> 6;
  __shared__ int wcnt[4];
  int base = 0;
  for (int c = 0; c < Tn * Kn; c += 256) {
    int f = c + tid;
    bool p = (ids[f] == e);
    unsigned long long m = __ballot(p);
    int rank = __popcll(m & ((1ull << lane) - 1ull));
    if (lane == 0) wcnt[wv] = __popcll(m);
    __syncthreads();
    int woff = 0;
    for (int w = 0; w < wv; ++w) woff += wcnt[w];
    int tot = wcnt[0] + wcnt[1] + wcnt[2] + wcnt[3];
    if (p) {
      int pos = base + woff + rank;
      if (pos < Cn) { etok[e * Cn + pos] = f / Kn; ewt[e * Cn + pos] = tw[f]; }
    }
    base += tot;
    __syncthreads();
  }
  int cc = base < Cn ? base : Cn;
  for (int cpos = cc + tid; cpos < Cn; cpos += 256) {
    etok[e * Cn + cpos] = -1; ewt[e * Cn + cpos] = 0.f;
  }
  if (tid == 0) ecnt[e] = cc;
}

// ---------------- GEMM1: (gathered) x @ W13, fused SiLU*mul, bf16 out ----------------
// 512 threads (8 waves x 16-row sub-tiles), BM=128, BN=64, BK=64.
// swzBits>0: 1D grid, XCD-aware decompose (whole expert on one XCD).
__global__ __launch_bounds__(512, 4)
void gemm1_silu(const float* __restrict__ A, const int* __restrict__ rows,
                const int* __restrict__ ecnt, const float* __restrict__ B,
                __bf16* __restrict__ O, int Kd, int Nhalf,
                long long Bstride, long long Ostride, int swzMode) {
  int e, m0, n0;
  if (swzMode) {
    // grid = 2048: xcd=hw&7, slot=hw>>3 (0..255); expert = xcd*8 + slot>>5
    int hw = blockIdx.x;
    int xcd = hw & 7, slot = hw >> 3;
    e = xcd * 8 + (slot >> 5);
    int within = slot & 31;          // 0..31: 2 msegs x 16 ntiles
    m0 = (within >> 4) * 128;
    n0 = (within & 15) * 64;
  } else {
    e = blockIdx.z; m0 = blockIdx.y * 128; n0 = blockIdx.x * 64;
  }
  if (ecnt && ecnt[e] <= m0) return;
  const float* Bp = B + (long long)e * Bstride;
  __bf16* Op = O + (long long)e * Ostride;

  __shared__ __attribute__((aligned(16))) __bf16 As[128 * 64];
  __shared__ __attribute__((aligned(16))) __bf16 Bg[64 * 64];
  __shared__ __attribute__((aligned(16))) __bf16 Bu[64 * 64];
  __shared__ int rowix[128];

  int tid = threadIdx.x;
  if (tid < 128) {
    int r;
    if (rows) { int v = rows[e * Cn + m0 + tid]; r = v < 0 ? 0 : v; }
    else r = m0 + tid;
    rowix[tid] = r;
  }
  __syncthreads();

  int lane = tid & 63;
  int wv = tid >> 6;                 // 0..7, wave owns rows [16*wv, 16*wv+16)
  int l15 = lane & 15, lhi = lane >> 4;

  // A staging: rowA = tid>>3 (0..63) and rowA+64; kc = (tid&7)*8 floats
  int rowA = tid >> 3, kc = (tid & 7) * 8, kcB = (tid & 7) * 16;
  const float* arow0 = A + (size_t)rowix[rowA] * Hn + kc;
  const float* arow1 = A + (size_t)rowix[rowA + 64] * Hn + kc;

  // B staging: threads 0-255 stage gate, 256-511 stage up
  int bt = tid & 255;
  int kb = (bt >> 4) * 4;            // 0..60
  int cB = (bt & 15) * 4;
  size_t ldb = (size_t)2 * Nhalf;
  const float* bsrc = Bp + (size_t)kb * ldb + n0 + cB + (tid >= 256 ? Nhalf : 0);
  __bf16* Bt = (tid >= 256) ? Bu : Bg;

  f32x4 zero = {0.f, 0.f, 0.f, 0.f};
  f32x4 accg[4], accu[4];
#pragma unroll
  for (int j = 0; j < 4; ++j) { accg[j] = zero; accu[j] = zero; }

  float4 qa0[2], qa1[2], qb[4];

#define LOADS(K0)                                                          \
  {                                                                        \
    qa0[0] = *(const float4*)(arow0 + (K0));                               \
    qa0[1] = *(const float4*)(arow0 + (K0) + 4);                           \
    qa1[0] = *(const float4*)(arow1 + (K0));                               \
    qa1[1] = *(const float4*)(arow1 + (K0) + 4);                           \
    _Pragma("unroll") for (int r = 0; r < 4; ++r)                          \
      qb[r] = *(const float4*)(bsrc + (size_t)((K0) + r) * ldb);           \
  }

  LOADS(0);

  for (int k0 = 0; k0 < Kd; k0 += 64) {
    // convert + LDS write
    {
      bf16x8 h0, h1;
#pragma unroll
      for (int j = 0; j < 4; ++j) {
        h0[j] = (__bf16)(((const float*)&qa0[0])[j]);
        h0[4 + j] = (__bf16)(((const float*)&qa0[1])[j]);
        h1[j] = (__bf16)(((const float*)&qa1[0])[j]);
        h1[4 + j] = (__bf16)(((const float*)&qa1[1])[j]);
      }
      *(bf16x8*)((char*)As + swz(rowA, kcB)) = h0;
      *(bf16x8*)((char*)As + swz(rowA + 64, kcB)) = h1;
    }
#pragma unroll
    for (int j = 0; j < 4; ++j) {
      bf16x4 cv;
#pragma unroll
      for (int r = 0; r < 4; ++r) cv[r] = (__bf16)(((const float*)&qb[r])[j]);
      *(bf16x4*)((char*)Bt + swz(cB + j, kb * 2)) = cv;
    }
    __syncthreads();

    if (k0 + 64 < Kd) LOADS(k0 + 64);   // prefetch next tile, in flight during MFMA

#pragma unroll
    for (int kk = 0; kk < 2; ++kk) {
      int kbyte = kk * 64 + 16 * lhi;
      bf16x8 af = *(const bf16x8*)((char*)As + swz(wv * 16 + l15, kbyte));
      bf16x8 fg[4], fu[4];
#pragma unroll
      for (int n = 0; n < 4; ++n) {
        fg[n] = *(const bf16x8*)((char*)Bg + swz(n * 16 + l15, kbyte));
        fu[n] = *(const bf16x8*)((char*)Bu + swz(n * 16 + l15, kbyte));
      }
#pragma unroll
      for (int n = 0; n < 4; ++n) {
        accg[n] = __builtin_amdgcn_mfma_f32_16x16x32_bf16(af, fg[n], accg[n], 0, 0, 0);
        accu[n] = __builtin_amdgcn_mfma_f32_16x16x32_bf16(af, fu[n], accu[n], 0, 0, 0);
      }
    }
    __syncthreads();
  }
#undef LOADS

#pragma unroll
  for (int n = 0; n < 4; ++n)
#pragma unroll
    for (int r = 0; r < 4; ++r) {
      int row = m0 + wv * 16 + lhi * 4 + r;
      int col = n0 + n * 16 + l15;
      float g = accg[n][r], u = accu[n][r];
      float v = g / (1.f + __expf(-g)) * u;
      Op[(size_t)row * Nhalf + col] = (__bf16)v;
    }
}

// ---------------- GEMM2: mid(bf16) @ W2/shared_down, scatter-atomic or store ----------------
// 256 threads (4 waves x 32-row sub-tiles), BM=128, BN=64, BK=64.
__global__ __launch_bounds__(256, 4)
void gemm2_kernel(const __bf16* __restrict__ A, const float* __restrict__ B,
                  const int* __restrict__ etok, const float* __restrict__ ewt,
                  const int* __restrict__ ecnt, float* __restrict__ out, int Kd,
                  long long Astride, long long Bstride, int swzMode) {
  int e, m0, n0;
  if (swzMode) {
    // grid = 4096: xcd=hw&7, slot=hw>>3 (0..511); expert = xcd*8 + slot>>6
    int hw = blockIdx.x;
    int xcd = hw & 7, slot = hw >> 3;
    e = xcd * 8 + (slot >> 6);
    int within = slot & 63;           // 2 msegs x 32 ntiles
    m0 = (within >> 5) * 128;
    n0 = (within & 31) * 64;
  } else {
    e = blockIdx.z; m0 = blockIdx.y * 128; n0 = blockIdx.x * 64;
  }
  if (ecnt && ecnt[e] <= m0) return;
  const __bf16* Ap = A + (long long)e * Astride;
  const float* Bp = B + (long long)e * Bstride;

  __shared__ __attribute__((aligned(16))) __bf16 As[128 * 64];
  __shared__ __attribute__((aligned(16))) __bf16 Bs[64 * 64];
  __shared__ int s_tok[128];
  __shared__ float s_wt[128];

  int tid = threadIdx.x;
  if (tid < 128) {
    if (etok) { s_tok[tid] = etok[e * Cn + m0 + tid]; s_wt[tid] = ewt[e * Cn + m0 + tid]; }
    else { s_tok[tid] = m0 + tid; s_wt[tid] = 1.f; }
  }
  __syncthreads();

  int lane = tid & 63;
  int wr = tid >> 6;
  int l15 = lane & 15, lhi = lane >> 4;

  int rowA = tid >> 3, kc8 = (tid & 7) * 8;
  const __bf16* ap0 = Ap + (size_t)(m0 + rowA) * Kd + kc8;

  int kb = (tid >> 4) * 4;
  int cB = (tid & 15) * 4;
  const float* bp0 = Bp + (size_t)kb * Hn + n0 + cB;

  f32x4 zero = {0.f, 0.f, 0.f, 0.f};
  f32x4 acc[2][4];
#pragma unroll
  for (int i = 0; i < 2; ++i)
#pragma unroll
    for (int j = 0; j < 4; ++j) acc[i][j] = zero;

  bf16x8 qa[4];
  float4 qb[4];

#define LOADS2(K0)                                                          \
  {                                                                         \
    _Pragma("unroll") for (int it = 0; it < 4; ++it)                        \
      qa[it] = *(const bf16x8*)(ap0 + (size_t)(32 * it) * Kd + (K0));       \
    _Pragma("unroll") for (int r = 0; r < 4; ++r)                           \
      qb[r] = *(const float4*)(bp0 + (size_t)((K0) + r) * Hn);              \
  }

  LOADS2(0);

  for (int k0 = 0; k0 < Kd; k0 += 64) {
#pragma unroll
    for (int it = 0; it < 4; ++it)
      *(bf16x8*)((char*)As + swz(rowA + 32 * it, kc8 * 2)) = qa[it];
#pragma unroll
    for (int j = 0; j < 4; ++j) {
      bf16x4 cv;
#pragma unroll
      for (int r = 0; r < 4; ++r) cv[r] = (__bf16)(((const float*)&qb[r])[j]);
      *(bf16x4*)((char*)Bs + swz(cB + j, kb * 2)) = cv;
    }
    __syncthreads();

    if (k0 + 64 < Kd) LOADS2(k0 + 64);

#pragma unroll
    for (int kk = 0; kk < 2; ++kk) {
      int kbyte = kk * 64 + 16 * lhi;
      bf16x8 af[2], bfr[4];
#pragma unroll
      for (int m = 0; m < 2; ++m)
        af[m] = *(const bf16x8*)((char*)As + swz(wr * 32 + m * 16 + l15, kbyte));
#pragma unroll
      for (int n = 0; n < 4; ++n)
        bfr[n] = *(const bf16x8*)((char*)Bs + swz(n * 16 + l15, kbyte));
#pragma unroll
      for (int m = 0; m < 2; ++m)
#pragma unroll
        for (int n = 0; n < 4; ++n)
          acc[m][n] = __builtin_amdgcn_mfma_f32_16x16x32_bf16(af[m], bfr[n], acc[m][n], 0, 0, 0);
    }
    __syncthreads();
  }
#undef LOADS2

#pragma unroll
  for (int m = 0; m < 2; ++m)
#pragma unroll
    for (int n = 0; n < 4; ++n)
#pragma unroll
      for (int r = 0; r < 4; ++r) {
        int lrow = wr * 32 + m * 16 + lhi * 4 + r;
        int col = n0 + n * 16 + l15;
        float v = acc[m][n][r];
        if (etok) {
          int tok = s_tok[lrow];
          if (tok >= 0) atomicAdd(out + (size_t)tok * Hn + col, s_wt[lrow] * v);
        } else {
          out[(size_t)(m0 + lrow) * Hn + col] = v;
        }
      }
}

extern "C" void kernel_launch(void* const* d_in, const int* in_sizes, int n_in,
                              void* d_out, int out_size, void* d_ws, size_t ws_size,
                              hipStream_t stream) {
  (void)in_sizes; (void)n_in; (void)out_size; (void)ws_size;
  const float* x   = (const float*)d_in[0];
  const float* gw  = (const float*)d_in[1];
  const float* gb  = (const float*)d_in[2];
  const float* w13 = (const float*)d_in[3];
  const float* w2  = (const float*)d_in[4];
  const float* sgu = (const float*)d_in[5];
  const float* sdn = (const float*)d_in[6];
  float* out = (float*)d_out;

  char* ws = (char*)d_ws;
  size_t off = 0;
  double* scores = (double*)(ws + off); off += (size_t)Tn * En * 8;
  int* ids   = (int*)(ws + off);   off += (size_t)Tn * Kn * 4;
  float* tw  = (float*)(ws + off); off += (size_t)Tn * Kn * 4;
  int* etok  = (int*)(ws + off);   off += (size_t)En * Cn * 4;
  float* ewt = (float*)(ws + off); off += (size_t)En * Cn * 4;
  int* ecnt  = (int*)(ws + off);   off += 256;
  __bf16* hmid = (__bf16*)(ws + off); off += (size_t)En * Cn * In * 2;
  __bf16* smid = (__bf16*)(ws + off); off += (size_t)Tn * Sn * 2;

  scores_kernel<<<Tn, 64, 0, stream>>>(x, gw, scores);
  topk_kernel<<<Tn / 256, 256, 0, stream>>>(scores, gb, ids, tw);
  dispatch_kernel<<<En, 256, 0, stream>>>(ids, tw, etok, ewt, ecnt);

  // expert gate_up + SiLU*mul -> hmid  [E,C,I] bf16   (XCD-swizzled 1D grid)
  gemm1_silu<<<dim3(2048, 1, 1), 512, 0, stream>>>(
      x, etok, ecnt, w13, hmid, Hn, In, (long long)Hn * 2 * In, (long long)Cn * In, 1);
  // shared gate_up + SiLU*mul -> smid  [T,S] bf16
  gemm1_silu<<<dim3(Sn / 64, Tn / 128, 1), 512, 0, stream>>>(
      x, nullptr, nullptr, sgu, smid, Hn, Sn, 0, 0, 0);
  // shared down -> out (direct store, initializes out)
  gemm2_kernel<<<dim3(Hn / 64, Tn / 128, 1), 256, 0, stream>>>(
      smid, sdn, nullptr, nullptr, nullptr, out, Sn, 0, 0, 0);
  // expert down -> scatter atomic add into out   (XCD-swizzled 1D grid)
  gemm2_kernel<<<dim3(4096, 1, 1), 256, 0, stream>>>(
      hmid, w2, etok, ewt, ecnt, out, In, (long long)Cn * In, (long long)In * Hn, 1);
}

// Round 4
// 641.791 us; speedup vs baseline: 3.3712x; 1.0168x over previous
//
#include <hip/hip_runtime.h>
#include <hip/hip_bf16.h>
#include <math.h>

#define Tn 1024
#define Hn 2048
#define En 64
#define Kn 6
#define In 1024
#define Gn 8
#define TGn 3
#define Cn 256
#define Sn 2048
#define RSF 2.5

typedef __bf16 bf16x8 __attribute__((ext_vector_type(8)));
typedef __bf16 bf16x4 __attribute__((ext_vector_type(4)));
typedef float f32x4 __attribute__((ext_vector_type(4)));

// swizzled byte offset within a [rows][64 bf16] (128B-row) LDS tile.
// XOR sel ((row^(row>>2))&7): 2-way max for both write patterns (stride-4 rows)
// and read patterns (consecutive rows).
__device__ __forceinline__ int swz(int row, int kbyte) {
  return row * 128 + (kbyte ^ ((((row >> 2) ^ row) & 7) << 4));
}

// one barrier per K-step: make LDS writes visible, never drain vmcnt.
#define BAR()                                                  \
  do {                                                         \
    asm volatile("s_waitcnt lgkmcnt(0)" ::: "memory");         \
    __builtin_amdgcn_sched_barrier(0);                         \
    __builtin_amdgcn_s_barrier();                              \
    __builtin_amdgcn_sched_barrier(0);                         \
  } while (0)

// ---------------- router: scores = sigmoid(x @ gate_w^T), fp64 accumulate ----------------
__global__ void scores_kernel(const float* __restrict__ x, const float* __restrict__ gw,
                              double* __restrict__ sc) {
  __shared__ float xs[Hn];
  int t = blockIdx.x;
  for (int i = threadIdx.x * 4; i < Hn; i += 64 * 4)
    *(float4*)(xs + i) = *(const float4*)(x + (size_t)t * Hn + i);
  __syncthreads();
  int e = threadIdx.x;
  const float* w = gw + (size_t)e * Hn;
  double a0 = 0.0, a1 = 0.0, a2 = 0.0, a3 = 0.0;
  for (int i = 0; i < Hn; i += 4) {
    float4 b = *(const float4*)(w + i);
    a0 += (double)xs[i] * b.x;
    a1 += (double)xs[i + 1] * b.y;
    a2 += (double)xs[i + 2] * b.z;
    a3 += (double)xs[i + 3] * b.w;
  }
  double acc = (a0 + a1) + (a2 + a3);
  sc[t * En + e] = 1.0 / (1.0 + exp(-acc));
}

// ---------------- grouped top-k (noaux_tc) ----------------
__global__ void topk_kernel(const double* __restrict__ sc_all, const float* __restrict__ bias,
                            int* __restrict__ ids, float* __restrict__ tw) {
  int t = blockIdx.x * blockDim.x + threadIdx.x;
  if (t >= Tn) return;
  const double* srow = sc_all + (size_t)t * En;
  double sc[En];
  for (int e = 0; e < En; ++e) sc[e] = srow[e] + (double)bias[e];
  double gsum[Gn];
  for (int g = 0; g < Gn; ++g) {
    double m1 = -1e300, m2 = -1e300;
    for (int j = 0; j < 8; ++j) {
      double v = sc[g * 8 + j];
      if (v > m1) { m2 = m1; m1 = v; } else if (v > m2) m2 = v;
    }
    gsum[g] = m1 + m2;
  }
  unsigned gsel = 0;
  for (int it = 0; it < TGn; ++it) {
    double best = -1e300; int bi = 0;
    for (int g = 0; g < Gn; ++g)
      if (!((gsel >> g) & 1) && gsum[g] > best) { best = gsum[g]; bi = g; }
    gsel |= 1u << bi;
  }
  unsigned long long taken = 0ull;
  int sel[Kn]; double w[Kn]; double wsum = 0.0;
  for (int k = 0; k < Kn; ++k) {
    double best = -1e300; int bi = 0;
    for (int e = 0; e < En; ++e) {
      if (!((gsel >> (e >> 3)) & 1)) continue;
      if ((taken >> e) & 1) continue;
      if (sc[e] > best) { best = sc[e]; bi = e; }
    }
    taken |= 1ull << bi;
    sel[k] = bi;
    w[k] = srow[bi];
    wsum += w[k];
  }
  double inv = RSF / (wsum + 1e-20);
  for (int k = 0; k < Kn; ++k) {
    ids[t * Kn + k] = sel[k];
    tw[t * Kn + k] = (float)(w[k] * inv);
  }
}

// ---------------- dispatch: parallel ballot-rank scan, cumsum position semantics ----------------
__global__ void dispatch_kernel(const int* __restrict__ ids, const float* __restrict__ tw,
                                int* __restrict__ etok, float* __restrict__ ewt,
                                int* __restrict__ ecnt) {
  int e = blockIdx.x;           // 64 blocks, one per expert
  int tid = threadIdx.x;        // 256 threads
  int lane = tid & 63, wv = tid >> 6;
  __shared__ int wcnt[4];
  int base = 0;
  for (int c = 0; c < Tn * Kn; c += 256) {
    int f = c + tid;
    bool p = (ids[f] == e);
    unsigned long long m = __ballot(p);
    int rank = __popcll(m & ((1ull << lane) - 1ull));
    if (lane == 0) wcnt[wv] = __popcll(m);
    __syncthreads();
    int woff = 0;
    for (int w = 0; w < wv; ++w) woff += wcnt[w];
    int tot = wcnt[0] + wcnt[1] + wcnt[2] + wcnt[3];
    if (p) {
      int pos = base + woff + rank;
      if (pos < Cn) { etok[e * Cn + pos] = f / Kn; ewt[e * Cn + pos] = tw[f]; }
    }
    base += tot;
    __syncthreads();
  }
  int cc = base < Cn ? base : Cn;
  for (int cpos = cc + tid; cpos < Cn; cpos += 256) {
    etok[e * Cn + cpos] = -1; ewt[e * Cn + cpos] = 0.f;
  }
  if (tid == 0) ecnt[e] = cc;
}

// ---------------- GEMM1: (gathered) x @ W13, fused SiLU*mul, bf16 out ----------------
// 512 threads (8 waves x 16-row sub-tiles), BM=128, BN=64+64, BK=64.
// Double-buffered LDS, ONE raw barrier per K-step, no vmcnt drain in loop.
__global__ __launch_bounds__(512, 4)
void gemm1_silu(const float* __restrict__ A, const int* __restrict__ rows,
                const int* __restrict__ ecnt, const float* __restrict__ B,
                __bf16* __restrict__ O, int Kd, int Nhalf,
                long long Bstride, long long Ostride, int swzMode) {
  int e, m0, n0;
  if (swzMode) {
    int hw = blockIdx.x;
    int xcd = hw & 7, slot = hw >> 3;
    e = xcd * 8 + (slot >> 5);
    int within = slot & 31;
    m0 = (within >> 4) * 128;
    n0 = (within & 15) * 64;
  } else {
    e = blockIdx.z; m0 = blockIdx.y * 128; n0 = blockIdx.x * 64;
  }
  if (ecnt && ecnt[e] <= m0) return;
  const float* Bp = B + (long long)e * Bstride;
  __bf16* Op = O + (long long)e * Ostride;

  __shared__ __attribute__((aligned(16))) __bf16 As[2][128 * 64];
  __shared__ __attribute__((aligned(16))) __bf16 Bg[2][64 * 64];
  __shared__ __attribute__((aligned(16))) __bf16 Bu[2][64 * 64];
  __shared__ int rowix[128];

  int tid = threadIdx.x;
  if (tid < 128) {
    int r;
    if (rows) { int v = rows[e * Cn + m0 + tid]; r = v < 0 ? 0 : v; }
    else r = m0 + tid;
    rowix[tid] = r;
  }
  __syncthreads();

  int lane = tid & 63;
  int wv = tid >> 6;                 // 0..7, wave owns rows [16*wv, 16*wv+16)
  int l15 = lane & 15, lhi = lane >> 4;

  int rowA = tid >> 3, kc = (tid & 7) * 8, kcB = (tid & 7) * 16;
  const float* arow0 = A + (size_t)rowix[rowA] * Hn + kc;
  const float* arow1 = A + (size_t)rowix[rowA + 64] * Hn + kc;

  int bt = tid & 255;
  int kb = (bt >> 4) * 4;
  int cB = (bt & 15) * 4;
  size_t ldb = (size_t)2 * Nhalf;
  const float* bsrc = Bp + (size_t)kb * ldb + n0 + cB + (tid >= 256 ? Nhalf : 0);

  f32x4 zero = {0.f, 0.f, 0.f, 0.f};
  f32x4 accg[4], accu[4];
#pragma unroll
  for (int j = 0; j < 4; ++j) { accg[j] = zero; accu[j] = zero; }

  float4 qa0[2], qa1[2], qb[4];

#define LOADS1(K0)                                                         \
  {                                                                        \
    qa0[0] = *(const float4*)(arow0 + (K0));                               \
    qa0[1] = *(const float4*)(arow0 + (K0) + 4);                           \
    qa1[0] = *(const float4*)(arow1 + (K0));                               \
    qa1[1] = *(const float4*)(arow1 + (K0) + 4);                           \
    _Pragma("unroll") for (int r = 0; r < 4; ++r)                          \
      qb[r] = *(const float4*)(bsrc + (size_t)((K0) + r) * ldb);           \
  }

#define WRITE1(P)                                                          \
  {                                                                        \
    bf16x8 h0, h1;                                                         \
    _Pragma("unroll") for (int j = 0; j < 4; ++j) {                        \
      h0[j] = (__bf16)(((const float*)&qa0[0])[j]);                        \
      h0[4 + j] = (__bf16)(((const float*)&qa0[1])[j]);                    \
      h1[j] = (__bf16)(((const float*)&qa1[0])[j]);                        \
      h1[4 + j] = (__bf16)(((const float*)&qa1[1])[j]);                    \
    }                                                                      \
    *(bf16x8*)((char*)As[P] + swz(rowA, kcB)) = h0;                        \
    *(bf16x8*)((char*)As[P] + swz(rowA + 64, kcB)) = h1;                   \
    __bf16* BtP = (tid >= 256) ? Bu[P] : Bg[P];                            \
    _Pragma("unroll") for (int j = 0; j < 4; ++j) {                        \
      bf16x4 cv;                                                           \
      _Pragma("unroll") for (int r = 0; r < 4; ++r)                        \
        cv[r] = (__bf16)(((const float*)&qb[r])[j]);                       \
      *(bf16x4*)((char*)BtP + swz(cB + j, kb * 2)) = cv;                   \
    }                                                                      \
  }

#define MFMA1(P)                                                           \
  _Pragma("unroll") for (int kk = 0; kk < 2; ++kk) {                       \
    int kbyte = kk * 64 + 16 * lhi;                                        \
    bf16x8 af = *(const bf16x8*)((char*)As[P] + swz(wv * 16 + l15, kbyte));\
    _Pragma("unroll") for (int n = 0; n < 4; ++n) {                        \
      bf16x8 fg = *(const bf16x8*)((char*)Bg[P] + swz(n * 16 + l15, kbyte)); \
      accg[n] = __builtin_amdgcn_mfma_f32_16x16x32_bf16(af, fg, accg[n], 0, 0, 0); \
      bf16x8 fu = *(const bf16x8*)((char*)Bu[P] + swz(n * 16 + l15, kbyte)); \
      accu[n] = __builtin_amdgcn_mfma_f32_16x16x32_bf16(af, fu, accu[n], 0, 0, 0); \
    }                                                                      \
  }

  int nt = Kd >> 6;
  LOADS1(0);
  WRITE1(0);
  LOADS1(64);
  BAR();
  for (int t = 0; t < nt; ++t) {
    int p = t & 1;
    __builtin_amdgcn_s_setprio(1);
    MFMA1(p);
    __builtin_amdgcn_s_setprio(0);
    if (t + 1 < nt) {
      WRITE1(p ^ 1);
      if (t + 2 < nt) LOADS1((t + 2) << 6);
    }
    BAR();
  }
#undef LOADS1
#undef WRITE1
#undef MFMA1

#pragma unroll
  for (int n = 0; n < 4; ++n)
#pragma unroll
    for (int r = 0; r < 4; ++r) {
      int row = m0 + wv * 16 + lhi * 4 + r;
      int col = n0 + n * 16 + l15;
      float g = accg[n][r], u = accu[n][r];
      float v = g / (1.f + __expf(-g)) * u;
      Op[(size_t)row * Nhalf + col] = (__bf16)v;
    }
}

// ---------------- GEMM2: mid(bf16) @ W2/shared_down, scatter-atomic or store ----------------
// 256 threads (4 waves x 32-row sub-tiles), BM=128, BN=64, BK=64. Same dbuf pipeline.
__global__ __launch_bounds__(256, 4)
void gemm2_kernel(const __bf16* __restrict__ A, const float* __restrict__ B,
                  const int* __restrict__ etok, const float* __restrict__ ewt,
                  const int* __restrict__ ecnt, float* __restrict__ out, int Kd,
                  long long Astride, long long Bstride, int swzMode) {
  int e, m0, n0;
  if (swzMode) {
    int hw = blockIdx.x;
    int xcd = hw & 7, slot = hw >> 3;
    e = xcd * 8 + (slot >> 6);
    int within = slot & 63;
    m0 = (within >> 5) * 128;
    n0 = (within & 31) * 64;
  } else {
    e = blockIdx.z; m0 = blockIdx.y * 128; n0 = blockIdx.x * 64;
  }
  if (ecnt && ecnt[e] <= m0) return;
  const __bf16* Ap = A + (long long)e * Astride;
  const float* Bp = B + (long long)e * Bstride;

  __shared__ __attribute__((aligned(16))) __bf16 As[2][128 * 64];
  __shared__ __attribute__((aligned(16))) __bf16 Bs[2][64 * 64];
  __shared__ int s_tok[128];
  __shared__ float s_wt[128];

  int tid = threadIdx.x;
  if (tid < 128) {
    if (etok) { s_tok[tid] = etok[e * Cn + m0 + tid]; s_wt[tid] = ewt[e * Cn + m0 + tid]; }
    else { s_tok[tid] = m0 + tid; s_wt[tid] = 1.f; }
  }
  __syncthreads();

  int lane = tid & 63;
  int wr = tid >> 6;
  int l15 = lane & 15, lhi = lane >> 4;

  int rowA = tid >> 3, kc8 = (tid & 7) * 8;
  const __bf16* ap0 = Ap + (size_t)(m0 + rowA) * Kd + kc8;

  int kb = (tid >> 4) * 4;
  int cB = (tid & 15) * 4;
  const float* bp0 = Bp + (size_t)kb * Hn + n0 + cB;

  f32x4 zero = {0.f, 0.f, 0.f, 0.f};
  f32x4 acc[2][4];
#pragma unroll
  for (int i = 0; i < 2; ++i)
#pragma unroll
    for (int j = 0; j < 4; ++j) acc[i][j] = zero;

  bf16x8 qa[4];
  float4 qb[4];

#define LOADS2(K0)                                                          \
  {                                                                         \
    _Pragma("unroll") for (int it = 0; it < 4; ++it)                        \
      qa[it] = *(const bf16x8*)(ap0 + (size_t)(32 * it) * Kd + (K0));       \
    _Pragma("unroll") for (int r = 0; r < 4; ++r)                           \
      qb[r] = *(const float4*)(bp0 + (size_t)((K0) + r) * Hn);              \
  }

#define WRITE2(P)                                                           \
  {                                                                         \
    _Pragma("unroll") for (int it = 0; it < 4; ++it)                        \
      *(bf16x8*)((char*)As[P] + swz(rowA + 32 * it, kc8 * 2)) = qa[it];     \
    _Pragma("unroll") for (int j = 0; j < 4; ++j) {                         \
      bf16x4 cv;                                                            \
      _Pragma("unroll") for (int r = 0; r < 4; ++r)                         \
        cv[r] = (__bf16)(((const float*)&qb[r])[j]);                        \
      *(bf16x4*)((char*)Bs[P] + swz(cB + j, kb * 2)) = cv;                  \
    }                                                                       \
  }

#define MFMA2(P)                                                            \
  _Pragma("unroll") for (int kk = 0; kk < 2; ++kk) {                        \
    int kbyte = kk * 64 + 16 * lhi;                                         \
    bf16x8 af0 = *(const bf16x8*)((char*)As[P] + swz(wr * 32 + l15, kbyte));       \
    bf16x8 af1 = *(const bf16x8*)((char*)As[P] + swz(wr * 32 + 16 + l15, kbyte));  \
    _Pragma("unroll") for (int n = 0; n < 4; ++n) {                         \
      bf16x8 bfr = *(const bf16x8*)((char*)Bs[P] + swz(n * 16 + l15, kbyte));      \
      acc[0][n] = __builtin_amdgcn_mfma_f32_16x16x32_bf16(af0, bfr, acc[0][n], 0, 0, 0); \
      acc[1][n] = __builtin_amdgcn_mfma_f32_16x16x32_bf16(af1, bfr, acc[1][n], 0, 0, 0); \
    }                                                                       \
  }

  int nt = Kd >> 6;
  LOADS2(0);
  WRITE2(0);
  LOADS2(64);
  BAR();
  for (int t = 0; t < nt; ++t) {
    int p = t & 1;
    __builtin_amdgcn_s_setprio(1);
    MFMA2(p);
    __builtin_amdgcn_s_setprio(0);
    if (t + 1 < nt) {
      WRITE2(p ^ 1);
      if (t + 2 < nt) LOADS2((t + 2) << 6);
    }
    BAR();
  }
#undef LOADS2
#undef WRITE2
#undef MFMA2

#pragma unroll
  for (int m = 0; m < 2; ++m)
#pragma unroll
    for (int n = 0; n < 4; ++n)
#pragma unroll
      for (int r = 0; r < 4; ++r) {
        int lrow = wr * 32 + m * 16 + lhi * 4 + r;
        int col = n0 + n * 16 + l15;
        float v = acc[m][n][r];
        if (etok) {
          int tok = s_tok[lrow];
          if (tok >= 0) atomicAdd(out + (size_t)tok * Hn + col, s_wt[lrow] * v);
        } else {
          out[(size_t)(m0 + lrow) * Hn + col] = v;
        }
      }
}

extern "C" void kernel_launch(void* const* d_in, const int* in_sizes, int n_in,
                              void* d_out, int out_size, void* d_ws, size_t ws_size,
                              hipStream_t stream) {
  (void)in_sizes; (void)n_in; (void)out_size; (void)ws_size;
  const float* x   = (const float*)d_in[0];
  const float* gw  = (const float*)d_in[1];
  const float* gb  = (const float*)d_in[2];
  const float* w13 = (const float*)d_in[3];
  const float* w2  = (const float*)d_in[4];
  const float* sgu = (const float*)d_in[5];
  const float* sdn = (const float*)d_in[6];
  float* out = (float*)d_out;

  char* ws = (char*)d_ws;
  size_t off = 0;
  double* scores = (double*)(ws + off); off += (size_t)Tn * En * 8;
  int* ids   = (int*)(ws + off);   off += (size_t)Tn * Kn * 4;
  float* tw  = (float*)(ws + off); off += (size_t)Tn * Kn * 4;
  int* etok  = (int*)(ws + off);   off += (size_t)En * Cn * 4;
  float* ewt = (float*)(ws + off); off += (size_t)En * Cn * 4;
  int* ecnt  = (int*)(ws + off);   off += 256;
  __bf16* hmid = (__bf16*)(ws + off); off += (size_t)En * Cn * In * 2;
  __bf16* smid = (__bf16*)(ws + off); off += (size_t)Tn * Sn * 2;

  scores_kernel<<<Tn, 64, 0, stream>>>(x, gw, scores);
  topk_kernel<<<Tn / 256, 256, 0, stream>>>(scores, gb, ids, tw);
  dispatch_kernel<<<En, 256, 0, stream>>>(ids, tw, etok, ewt, ecnt);

  // expert gate_up + SiLU*mul -> hmid  [E,C,I] bf16   (XCD-swizzled 1D grid)
  gemm1_silu<<<dim3(2048, 1, 1), 512, 0, stream>>>(
      x, etok, ecnt, w13, hmid, Hn, In, (long long)Hn * 2 * In, (long long)Cn * In, 1);
  // shared gate_up + SiLU*mul -> smid  [T,S] bf16
  gemm1_silu<<<dim3(Sn / 64, Tn / 128, 1), 512, 0, stream>>>(
      x, nullptr, nullptr, sgu, smid, Hn, Sn, 0, 0, 0);
  // shared down -> out (direct store, initializes out)
  gemm2_kernel<<<dim3(Hn / 64, Tn / 128, 1), 256, 0, stream>>>(
      smid, sdn, nullptr, nullptr, nullptr, out, Sn, 0, 0, 0);
  // expert down -> scatter atomic add into out   (XCD-swizzled 1D grid)
  gemm2_kernel<<<dim3(4096, 1, 1), 256, 0, stream>>>(
      hmid, w2, etok, ewt, ecnt, out, In, (long long)Cn * In, (long long)In * Hn, 1);
}